// Round 9
// baseline (297.258 us; speedup 1.0000x reference)
//
#include <hip/hip_runtime.h>
#include <hip/hip_fp16.h>

#define N_NODES 100000
#define E_EDGES 1600000
#define NCLS 10

#define BW 128                       // bucket width in nodes
#define NB 782                       // ceil(N_NODES / BW)
#define EPB 8192                     // edges per binning block
#define NBLK_BIN 196                 // ceil(E_EDGES / EPB)

// ------- per-block bucket histogram (no global atomics) -------------------
__global__ __launch_bounds__(256) void k_hist(const int* __restrict__ col,
                                              int* __restrict__ blockHist) {
    __shared__ int h[NB];
    int t = threadIdx.x;
    for (int i = t; i < NB; i += 256) h[i] = 0;
    __syncthreads();
    int base = blockIdx.x * EPB;
    int end  = min(base + EPB, E_EDGES);
    for (int e = base + t; e < end; e += 256)
        atomicAdd(&h[col[e] >> 7], 1);
    __syncthreads();
    for (int i = t; i < NB; i += 256)
        blockHist[blockIdx.x * NB + i] = h[i];
}

// ------- block 0: deterministic offsets scan; block 1: W12/c1 -------------
__global__ __launch_bounds__(1024) void k_scan_w12(int* __restrict__ blockHist,
                                                   int* __restrict__ bucketBase,
                                                   const float* __restrict__ W1,
                                                   const float* __restrict__ W2,
                                                   const float* __restrict__ b1,
                                                   float* __restrict__ W12,
                                                   float* __restrict__ c1) {
    __shared__ int   s[1024];
    __shared__ float w2s[1280];
    int t = threadIdx.x;
    if (blockIdx.x == 0) {
        int run = 0;
        if (t < NB) {
            for (int b = 0; b < NBLK_BIN; ++b) {
                int v = blockHist[b * NB + t];
                blockHist[b * NB + t] = run;   // per-bucket exclusive over blocks
                run += v;
            }
        }
        s[t] = (t < NB) ? run : 0;
        __syncthreads();
        for (int st = 1; st < 1024; st <<= 1) {
            int tmp = (t >= st) ? s[t - st] : 0;
            __syncthreads();
            s[t] += tmp;
            __syncthreads();
        }
        if (t < NB) bucketBase[t] = s[t] - run;   // exclusive
        if (t == NB - 1) bucketBase[NB] = s[t];   // = E_EDGES
    } else {
        for (int i = t; i < 1280; i += 1024) w2s[i] = W2[i];
        __syncthreads();
        if (t < 128) {
            float acc[NCLS];
            #pragma unroll
            for (int j = 0; j < NCLS; ++j) acc[j] = 0.f;
            for (int m = 0; m < 128; ++m) {
                float w1mk = W1[m * 128 + t];    // coalesced column read
                #pragma unroll
                for (int j = 0; j < NCLS; ++j) acc[j] += w2s[j * 128 + m] * w1mk;
            }
            #pragma unroll
            for (int j = 0; j < NCLS; ++j) W12[j * 128 + t] = acc[j];
        } else if (t < 144) {
            int j = t - 128;
            float acc = 0.f;
            if (j < NCLS)
                for (int m = 0; m < 128; ++m) acc += W2[j * 128 + m] * b1[m];
            c1[j] = (j < NCLS) ? acc : 0.f;
        }
    }
}

// ------- bin edges into bucketed packed array (deterministic chunks) ------
__global__ __launch_bounds__(256) void k_bin(const int* __restrict__ ei,
                                             const int* __restrict__ blockHist,
                                             const int* __restrict__ bucketBase,
                                             unsigned* __restrict__ binned) {
    __shared__ int h[NB];
    __shared__ int chunk[NB];
    int t = threadIdx.x;
    for (int i = t; i < NB; i += 256) {
        h[i] = 0;
        chunk[i] = bucketBase[i] + blockHist[blockIdx.x * NB + i];
    }
    __syncthreads();
    int base = blockIdx.x * EPB;
    int end  = min(base + EPB, E_EDGES);
    const int* col = ei + E_EDGES;
    for (int e = base + t; e < end; e += 256) {
        int c = col[e];
        int r = ei[e];
        int k = c >> 7;
        int slot = chunk[k] + atomicAdd(&h[k], 1);   // LDS-local rank only
        binned[slot] = ((unsigned)r << 7) | (unsigned)(c & 127);
    }
}

// ------- per-bucket degree count -> dis ----------------------------------
__global__ __launch_bounds__(256) void k_deg(const unsigned* __restrict__ binned,
                                             const int* __restrict__ bucketBase,
                                             float* __restrict__ dis) {
    __shared__ int cnt[BW];
    int k = blockIdx.x, t = threadIdx.x;
    if (t < BW) cnt[t] = 0;
    __syncthreads();
    int s0 = bucketBase[k], s1 = bucketBase[k + 1];
    for (int i = s0 + t; i < s1; i += 256)
        atomicAdd(&cnt[binned[i] & 127], 1);
    __syncthreads();
    int node = k * BW + t;
    if (t < BW && node < N_NODES) dis[node] = rsqrtf((float)(cnt[t] + 1));
}

// ------- g1h = fp16( dis .* (x @ W12^T) ), rows of 32B (20B used) ---------
__global__ __launch_bounds__(64) void k_g1(const float* __restrict__ x,
                                           const float* __restrict__ dis,
                                           const float* __restrict__ W12,
                                           __half2* __restrict__ g1h) {
    int row = blockIdx.x * 64 + threadIdx.x;
    if (row >= N_NODES) return;

    const float4* x4 = (const float4*)x;
    float acc[NCLS];
    #pragma unroll
    for (int j = 0; j < NCLS; ++j) acc[j] = 0.f;

    #pragma unroll
    for (int k4 = 0; k4 < 32; ++k4) {
        float4 xv = x4[row * 32 + k4];
        #pragma unroll
        for (int j = 0; j < NCLS; ++j) {
            const float* wj = &W12[j * 128 + k4 * 4];   // uniform addr -> s_load
            acc[j] += xv.x * wj[0] + xv.y * wj[1] + xv.z * wj[2] + xv.w * wj[3];
        }
    }

    float d = dis[row];
    unsigned w[5];
    #pragma unroll
    for (int j = 0; j < 5; ++j) {
        __half2 hv = __floats2half2_rn(d * acc[2 * j], d * acc[2 * j + 1]);
        w[j] = *(unsigned*)&hv;
    }
    unsigned* u = (unsigned*)g1h;
    uint4 head = {w[0], w[1], w[2], w[3]};
    *(uint4*)&u[row * 8] = head;
    u[row * 8 + 4] = w[4];
}

static __device__ __forceinline__ float2 h2f(unsigned u) {
    return __half22float2(*reinterpret_cast<__half2*>(&u));
}

// ------- agg A fused: LDS-accumulate per bucket; h2h = fp16(dc*(dc*acc+c1))
__global__ __launch_bounds__(256) void k_agg_a(const __half2* __restrict__ g1h,
                                               const float* __restrict__ dis,
                                               const unsigned* __restrict__ binned,
                                               const int* __restrict__ bucketBase,
                                               const float* __restrict__ c1,
                                               __half2* __restrict__ h2h) {
    __shared__ float accf[BW * 10];
    int k = blockIdx.x, t = threadIdx.x;
    const uint4*     g4 = (const uint4*)g1h;
    const unsigned*  gu = (const unsigned*)g1h;

    if (t < BW) {                       // init with pre-scaled self row
        int c = k * BW + t;
        float* d = &accf[t * 10];
        if (c < N_NODES) {
            uint4 a = g4[c * 2];
            unsigned b = gu[c * 8 + 4];
            float2 f;
            f = h2f(a.x); d[0] = f.x; d[1] = f.y;
            f = h2f(a.y); d[2] = f.x; d[3] = f.y;
            f = h2f(a.z); d[4] = f.x; d[5] = f.y;
            f = h2f(a.w); d[6] = f.x; d[7] = f.y;
            f = h2f(b);   d[8] = f.x; d[9] = f.y;
        } else {
            #pragma unroll
            for (int j = 0; j < 10; ++j) d[j] = 0.f;
        }
    }
    __syncthreads();

    int s0 = bucketBase[k], s1 = bucketBase[k + 1];
    #pragma unroll 2
    for (int i = s0 + t; i < s1; i += 256) {
        unsigned p = binned[i];
        int r = p >> 7;
        float* d = &accf[(p & 127) * 10];
        uint4 a = g4[r * 2];
        unsigned b = gu[r * 8 + 4];
        float2 f;
        f = h2f(a.x); atomicAdd(&d[0], f.x); atomicAdd(&d[1], f.y);
        f = h2f(a.y); atomicAdd(&d[2], f.x); atomicAdd(&d[3], f.y);
        f = h2f(a.z); atomicAdd(&d[4], f.x); atomicAdd(&d[5], f.y);
        f = h2f(a.w); atomicAdd(&d[6], f.x); atomicAdd(&d[7], f.y);
        f = h2f(b);   atomicAdd(&d[8], f.x); atomicAdd(&d[9], f.y);
    }
    __syncthreads();

    if (t < BW) {
        int c = k * BW + t;
        if (c < N_NODES) {
            float dc = dis[c];
            const float* d = &accf[t * 10];
            unsigned w[5];
            #pragma unroll
            for (int j = 0; j < 5; ++j) {
                __half2 hv = __floats2half2_rn(dc * (dc * d[2 * j]     + c1[2 * j]),
                                               dc * (dc * d[2 * j + 1] + c1[2 * j + 1]));
                w[j] = *(unsigned*)&hv;
            }
            unsigned* u = (unsigned*)h2h;
            uint4 head = {w[0], w[1], w[2], w[3]};
            *(uint4*)&u[c * 8] = head;
            u[c * 8 + 4] = w[4];
        }
    }
}

// ------- agg B fused: out = dc*acc + b2 (f32 N x 10) ----------------------
__global__ __launch_bounds__(256) void k_agg_b(const __half2* __restrict__ h2h,
                                               const float* __restrict__ dis,
                                               const unsigned* __restrict__ binned,
                                               const int* __restrict__ bucketBase,
                                               const float* __restrict__ b2,
                                               float* __restrict__ out) {
    __shared__ float accf[BW * 10];
    int k = blockIdx.x, t = threadIdx.x;
    const uint4*     g4 = (const uint4*)h2h;
    const unsigned*  gu = (const unsigned*)h2h;

    if (t < BW) {
        int c = k * BW + t;
        float* d = &accf[t * 10];
        if (c < N_NODES) {
            uint4 a = g4[c * 2];
            unsigned b = gu[c * 8 + 4];
            float2 f;
            f = h2f(a.x); d[0] = f.x; d[1] = f.y;
            f = h2f(a.y); d[2] = f.x; d[3] = f.y;
            f = h2f(a.z); d[4] = f.x; d[5] = f.y;
            f = h2f(a.w); d[6] = f.x; d[7] = f.y;
            f = h2f(b);   d[8] = f.x; d[9] = f.y;
        } else {
            #pragma unroll
            for (int j = 0; j < 10; ++j) d[j] = 0.f;
        }
    }
    __syncthreads();

    int s0 = bucketBase[k], s1 = bucketBase[k + 1];
    #pragma unroll 2
    for (int i = s0 + t; i < s1; i += 256) {
        unsigned p = binned[i];
        int r = p >> 7;
        float* d = &accf[(p & 127) * 10];
        uint4 a = g4[r * 2];
        unsigned b = gu[r * 8 + 4];
        float2 f;
        f = h2f(a.x); atomicAdd(&d[0], f.x); atomicAdd(&d[1], f.y);
        f = h2f(a.y); atomicAdd(&d[2], f.x); atomicAdd(&d[3], f.y);
        f = h2f(a.z); atomicAdd(&d[4], f.x); atomicAdd(&d[5], f.y);
        f = h2f(a.w); atomicAdd(&d[6], f.x); atomicAdd(&d[7], f.y);
        f = h2f(b);   atomicAdd(&d[8], f.x); atomicAdd(&d[9], f.y);
    }
    __syncthreads();

    if (t < BW) {
        int c = k * BW + t;
        if (c < N_NODES) {
            float dc = dis[c];
            const float* d = &accf[t * 10];
            #pragma unroll
            for (int j = 0; j < 5; ++j) {
                float2 o;
                o.x = dc * d[2 * j]     + b2[2 * j];
                o.y = dc * d[2 * j + 1] + b2[2 * j + 1];
                *(float2*)&out[c * NCLS + 2 * j] = o;
            }
        }
    }
}

extern "C" void kernel_launch(void* const* d_in, const int* in_sizes, int n_in,
                              void* d_out, int out_size, void* d_ws, size_t ws_size,
                              hipStream_t stream) {
    const float* x  = (const float*)d_in[0];
    const int*   ei = (const int*)d_in[1];   // [2, E] int32
    const float* W1 = (const float*)d_in[2];
    const float* b1 = (const float*)d_in[3];
    const float* W2 = (const float*)d_in[4];
    const float* b2 = (const float*)d_in[5];
    float* out = (float*)d_out;

    char* ws = (char*)d_ws;
    int*      bucketBase = (int*)(ws + 0);                  // NB+1 ints
    float*    W12        = (float*)(ws + 4096);             // 5 KB
    float*    c1         = (float*)(ws + 16384);            // 64 B (16 padded)
    int*      blockHist  = (int*)(ws + 32768);              // 196*782 ints ~600 KB
    float*    dis        = (float*)(ws + (1 << 20));        // 400 KB
    unsigned* binned     = (unsigned*)(ws + (2 << 20));     // 6.4 MB
    __half2*  g1h        = (__half2*)(ws + (12 << 20));     // 3.2 MB
    __half2*  h2h        = (__half2*)(ws + (16 << 20));     // 3.2 MB

    k_hist<<<NBLK_BIN, 256, 0, stream>>>(ei + E_EDGES, blockHist);
    k_scan_w12<<<2, 1024, 0, stream>>>(blockHist, bucketBase, W1, W2, b1, W12, c1);
    k_bin<<<NBLK_BIN, 256, 0, stream>>>(ei, blockHist, bucketBase, binned);
    k_deg<<<NB, 256, 0, stream>>>(binned, bucketBase, dis);

    k_g1<<<(N_NODES + 63) / 64, 64, 0, stream>>>(x, dis, W12, g1h);

    k_agg_a<<<NB, 256, 0, stream>>>(g1h, dis, binned, bucketBase, c1, h2h);
    k_agg_b<<<NB, 256, 0, stream>>>(h2h, dis, binned, bucketBase, b2, out);
}

// Round 10
// 113.896 us; speedup vs baseline: 2.6099x; 2.6099x over previous
//
#include <hip/hip_runtime.h>
#include <hip/hip_fp16.h>

#define N_NODES 100000
#define E_EDGES 1600000
#define NCLS 10

#define BW 256                       // bucket width in nodes
#define NB 391                       // ceil(N_NODES / BW)
#define EPB 8192                     // edges per binning block
#define NBLK_BIN 196                 // ceil(E_EDGES / EPB)

// ------- per-block bucket histogram (no global atomics) -------------------
__global__ __launch_bounds__(256) void k_hist(const int* __restrict__ col,
                                              int* __restrict__ blockHist) {
    __shared__ int h[NB];
    int t = threadIdx.x;
    for (int i = t; i < NB; i += 256) h[i] = 0;
    __syncthreads();
    int base = blockIdx.x * EPB;
    int end  = min(base + EPB, E_EDGES);
    for (int e = base + t; e < end; e += 256)
        atomicAdd(&h[col[e] >> 8], 1);
    __syncthreads();
    for (int i = t; i < NB; i += 256)
        blockHist[blockIdx.x * NB + i] = h[i];
}

// ------- block 0: deterministic offset scan; block 1: W12 = W2@W1, c1 -----
__global__ __launch_bounds__(512) void k_scan_w12(int* __restrict__ blockHist,
                                                  int* __restrict__ bucketBase,
                                                  const float* __restrict__ W1,
                                                  const float* __restrict__ W2,
                                                  const float* __restrict__ b1,
                                                  float* __restrict__ W12,
                                                  float* __restrict__ c1) {
    __shared__ int   s[512];
    __shared__ float w2s[1280];
    int t = threadIdx.x;
    if (blockIdx.x == 0) {
        int run = 0;
        if (t < NB) {
            for (int b = 0; b < NBLK_BIN; ++b) {
                int v = blockHist[b * NB + t];
                blockHist[b * NB + t] = run;   // per-bucket exclusive over blocks
                run += v;
            }
        }
        s[t] = (t < NB) ? run : 0;
        __syncthreads();
        for (int st = 1; st < 512; st <<= 1) {
            int tmp = (t >= st) ? s[t - st] : 0;
            __syncthreads();
            s[t] += tmp;
            __syncthreads();
        }
        if (t < NB) bucketBase[t] = s[t] - run;   // exclusive
        if (t == NB - 1) bucketBase[NB] = s[t];   // = E_EDGES
    } else {
        for (int i = t; i < 1280; i += 512) w2s[i] = W2[i];
        __syncthreads();
        if (t < 128) {
            float acc[NCLS];
            #pragma unroll
            for (int j = 0; j < NCLS; ++j) acc[j] = 0.f;
            for (int m = 0; m < 128; ++m) {
                float w1mk = W1[m * 128 + t];    // coalesced column read
                #pragma unroll
                for (int j = 0; j < NCLS; ++j) acc[j] += w2s[j * 128 + m] * w1mk;
            }
            #pragma unroll
            for (int j = 0; j < NCLS; ++j) W12[j * 128 + t] = acc[j];
        } else if (t < 144) {
            int j = t - 128;
            float acc = 0.f;
            if (j < NCLS)
                for (int m = 0; m < 128; ++m) acc += W2[j * 128 + m] * b1[m];
            c1[j] = (j < NCLS) ? acc : 0.f;
        }
    }
}

// ------- bin edges into bucketed packed array (deterministic chunks) ------
__global__ __launch_bounds__(256) void k_bin(const int* __restrict__ ei,
                                             const int* __restrict__ blockHist,
                                             const int* __restrict__ bucketBase,
                                             unsigned* __restrict__ binned) {
    __shared__ int h[NB];
    __shared__ int chunk[NB];
    int t = threadIdx.x;
    for (int i = t; i < NB; i += 256) {
        h[i] = 0;
        chunk[i] = bucketBase[i] + blockHist[blockIdx.x * NB + i];
    }
    __syncthreads();
    int base = blockIdx.x * EPB;
    int end  = min(base + EPB, E_EDGES);
    const int* col = ei + E_EDGES;
    for (int e = base + t; e < end; e += 256) {
        int c = col[e];
        int r = ei[e];
        int k = c >> 8;
        int slot = chunk[k] + atomicAdd(&h[k], 1);   // LDS-local rank only
        binned[slot] = ((unsigned)r << 8) | (unsigned)(c & 255);
    }
}

// ---------------- per-bucket: degrees, offs, dis, csr fill ----------------
__global__ __launch_bounds__(256) void k_build(const unsigned* __restrict__ binned,
                                               const int* __restrict__ bucketBase,
                                               int* __restrict__ degi,
                                               int* __restrict__ offs,
                                               float* __restrict__ dis,
                                               int* __restrict__ csr) {
    __shared__ int cnt[BW];
    __shared__ int sc[BW];
    __shared__ int eoff[BW];
    __shared__ int cur[BW];
    int k = blockIdx.x;
    int t = threadIdx.x;
    cnt[t] = 0;
    __syncthreads();
    int s0 = bucketBase[k], s1 = bucketBase[k + 1];
    for (int i = s0 + t; i < s1; i += 256)
        atomicAdd(&cnt[binned[i] & 255], 1);
    __syncthreads();
    int v = cnt[t];
    sc[t] = v;
    __syncthreads();
    for (int st = 1; st < 256; st <<= 1) {
        int tmp = (t >= st) ? sc[t - st] : 0;
        __syncthreads();
        sc[t] += tmp;
        __syncthreads();
    }
    eoff[t] = sc[t] - v;   // exclusive
    cur[t] = 0;
    int node = k * BW + t;
    if (node < N_NODES) {
        degi[node] = v;
        offs[node] = s0 + eoff[t];
        dis[node]  = rsqrtf((float)(v + 1));
    }
    __syncthreads();
    for (int i = s0 + t; i < s1; i += 256) {
        unsigned p = binned[i];
        int lc = p & 255;
        int r  = p >> 8;
        int pos = s0 + eoff[lc] + atomicAdd(&cur[lc], 1);
        csr[pos] = r;
    }
}

// ------- g1h = fp16( dis .* (x @ W12^T) ), rows of 16 halfs (32B) ---------
// thread-per-row: 32 float4 streaming loads, W12 via wave-uniform s_load.
__global__ __launch_bounds__(64) void k_g1(const float* __restrict__ x,
                                           const float* __restrict__ dis,
                                           const float* __restrict__ W12,
                                           __half2* __restrict__ g1h) {
    int row = blockIdx.x * 64 + threadIdx.x;
    if (row >= N_NODES) return;

    const float4* x4 = (const float4*)x;
    float acc[NCLS];
    #pragma unroll
    for (int j = 0; j < NCLS; ++j) acc[j] = 0.f;

    #pragma unroll
    for (int k4 = 0; k4 < 32; ++k4) {
        float4 xv = x4[row * 32 + k4];
        #pragma unroll
        for (int j = 0; j < NCLS; ++j) {
            const float* wj = &W12[j * 128 + k4 * 4];   // uniform addr -> s_load
            acc[j] += xv.x * wj[0] + xv.y * wj[1] + xv.z * wj[2] + xv.w * wj[3];
        }
    }

    float d = dis[row];
    __half2 hp[8];
    #pragma unroll
    for (int j = 0; j < 5; ++j)
        hp[j] = __floats2half2_rn(d * acc[2 * j], d * acc[2 * j + 1]);
    hp[5] = __floats2half2_rn(0.f, 0.f);
    hp[6] = hp[5];
    hp[7] = hp[5];
    uint4* dst = (uint4*)&g1h[row * 8];
    dst[0] = *(const uint4*)&hp[0];
    dst[1] = *(const uint4*)&hp[4];
}

// ------- agg A: h2h = fp16( dc*(dc*acc + c1) ), acc = sum of scaled rows --
// 8-lane groups; lane j covers feats {2j, 2j+1}; f32 accumulation.
__global__ __launch_bounds__(256) void k_agg_a(const __half2* __restrict__ g1h,
                                               const float* __restrict__ dis,
                                               const int* __restrict__ csr,
                                               const int* __restrict__ offs,
                                               const int* __restrict__ degi,
                                               const float* __restrict__ c1,
                                               __half2* __restrict__ h2h) {
    int c = blockIdx.x * 32 + (threadIdx.x >> 3);
    int j = threadIdx.x & 7;
    if (c >= N_NODES) return;

    float2 acc = __half22float2(g1h[c * 8 + j]);   // self (pre-scaled)

    int start = offs[c];
    int deg   = degi[c];
    int k = 0;
    for (; k + 4 <= deg; k += 4) {
        int r0 = csr[start + k + 0];
        int r1 = csr[start + k + 1];
        int r2 = csr[start + k + 2];
        int r3 = csr[start + k + 3];
        float2 a0 = __half22float2(g1h[r0 * 8 + j]);
        float2 a1 = __half22float2(g1h[r1 * 8 + j]);
        float2 a2 = __half22float2(g1h[r2 * 8 + j]);
        float2 a3 = __half22float2(g1h[r3 * 8 + j]);
        acc.x += (a0.x + a1.x) + (a2.x + a3.x);
        acc.y += (a0.y + a1.y) + (a2.y + a3.y);
    }
    for (; k < deg; ++k) {
        float2 a = __half22float2(g1h[csr[start + k] * 8 + j]);
        acc.x += a.x;
        acc.y += a.y;
    }

    float dc = dis[c];
    float ox = dc * (dc * acc.x + c1[2 * j]);       // j>=5: acc=0,c1=0 -> 0
    float oy = dc * (dc * acc.y + c1[2 * j + 1]);
    h2h[c * 8 + j] = __floats2half2_rn(ox, oy);
}

// ------- agg B: out = dc*acc + b2 (compact N x 10 f32 output) -------------
__global__ __launch_bounds__(256) void k_agg_b(const __half2* __restrict__ h2h,
                                               const float* __restrict__ dis,
                                               const int* __restrict__ csr,
                                               const int* __restrict__ offs,
                                               const int* __restrict__ degi,
                                               const float* __restrict__ b2,
                                               float* __restrict__ out) {
    int c = blockIdx.x * 32 + (threadIdx.x >> 3);
    int j = threadIdx.x & 7;
    if (c >= N_NODES) return;

    float2 acc = __half22float2(h2h[c * 8 + j]);   // self (pre-scaled)

    int start = offs[c];
    int deg   = degi[c];
    int k = 0;
    for (; k + 4 <= deg; k += 4) {
        int r0 = csr[start + k + 0];
        int r1 = csr[start + k + 1];
        int r2 = csr[start + k + 2];
        int r3 = csr[start + k + 3];
        float2 a0 = __half22float2(h2h[r0 * 8 + j]);
        float2 a1 = __half22float2(h2h[r1 * 8 + j]);
        float2 a2 = __half22float2(h2h[r2 * 8 + j]);
        float2 a3 = __half22float2(h2h[r3 * 8 + j]);
        acc.x += (a0.x + a1.x) + (a2.x + a3.x);
        acc.y += (a0.y + a1.y) + (a2.y + a3.y);
    }
    for (; k < deg; ++k) {
        float2 a = __half22float2(h2h[csr[start + k] * 8 + j]);
        acc.x += a.x;
        acc.y += a.y;
    }

    if (j < 5) {
        float dc = dis[c];
        float2 o;
        o.x = dc * acc.x + b2[2 * j];
        o.y = dc * acc.y + b2[2 * j + 1];
        *(float2*)&out[c * NCLS + 2 * j] = o;
    }
}

extern "C" void kernel_launch(void* const* d_in, const int* in_sizes, int n_in,
                              void* d_out, int out_size, void* d_ws, size_t ws_size,
                              hipStream_t stream) {
    const float* x  = (const float*)d_in[0];
    const int*   ei = (const int*)d_in[1];   // [2, E] int32
    const float* W1 = (const float*)d_in[2];
    const float* b1 = (const float*)d_in[3];
    const float* W2 = (const float*)d_in[4];
    const float* b2 = (const float*)d_in[5];
    float* out = (float*)d_out;

    char* ws = (char*)d_ws;
    int*      bucketBase = (int*)(ws + 0);                  // NB+1 ints
    float*    W12        = (float*)(ws + 4096);             // 5 KB
    float*    c1         = (float*)(ws + 16384);            // 64 B (16 padded)
    int*      blockHist  = (int*)(ws + 32768);              // 196*391 ints ~300 KB
    int*      degi       = (int*)(ws + (1 << 20));          // 400 KB
    int*      offs       = (int*)(ws + (2 << 20));          // 400 KB
    float*    dis        = (float*)(ws + (3 << 20));        // 400 KB
    unsigned* binned     = (unsigned*)(ws + (4 << 20));     // 6.4 MB
    int*      csr        = (int*)(ws + (12 << 20));         // 6.4 MB
    __half2*  g1h        = (__half2*)(ws + (20 << 20));     // 3.2 MB
    __half2*  h2h        = (__half2*)(ws + (24 << 20));     // 3.2 MB

    k_hist<<<NBLK_BIN, 256, 0, stream>>>(ei + E_EDGES, blockHist);
    k_scan_w12<<<2, 512, 0, stream>>>(blockHist, bucketBase, W1, W2, b1, W12, c1);
    k_bin<<<NBLK_BIN, 256, 0, stream>>>(ei, blockHist, bucketBase, binned);
    k_build<<<NB, 256, 0, stream>>>(binned, bucketBase, degi, offs, dis, csr);

    k_g1<<<(N_NODES + 63) / 64, 64, 0, stream>>>(x, dis, W12, g1h);

    k_agg_a<<<(N_NODES + 31) / 32, 256, 0, stream>>>(g1h, dis, csr, offs, degi, c1, h2h);
    k_agg_b<<<(N_NODES + 31) / 32, 256, 0, stream>>>(h2h, dis, csr, offs, degi, b2, out);
}

// Round 11
// 105.906 us; speedup vs baseline: 2.8068x; 1.0754x over previous
//
#include <hip/hip_runtime.h>
#include <hip/hip_fp16.h>

#define N_NODES 100000
#define E_EDGES 1600000
#define NCLS 10

#define BW 256                       // bucket width in nodes
#define NB 391                       // ceil(N_NODES / BW)
#define EPB 8192                     // edges per binning block
#define NBLK_BIN 196                 // ceil(E_EDGES / EPB)

// ------- per-block bucket histogram (no global atomics) -------------------
__global__ __launch_bounds__(256) void k_hist(const int* __restrict__ col,
                                              int* __restrict__ blockHist) {
    __shared__ int h[NB];
    int t = threadIdx.x;
    for (int i = t; i < NB; i += 256) h[i] = 0;
    __syncthreads();
    int base = blockIdx.x * EPB;
    int end  = min(base + EPB, E_EDGES);
    for (int e = base + t; e < end; e += 256)
        atomicAdd(&h[col[e] >> 8], 1);
    __syncthreads();
    for (int i = t; i < NB; i += 256)
        blockHist[blockIdx.x * NB + i] = h[i];
}

// ------- block 0: deterministic offset scan; block 1: W12 = W2@W1, c1 -----
__global__ __launch_bounds__(512) void k_scan_w12(int* __restrict__ blockHist,
                                                  int* __restrict__ bucketBase,
                                                  const float* __restrict__ W1,
                                                  const float* __restrict__ W2,
                                                  const float* __restrict__ b1,
                                                  float* __restrict__ W12,
                                                  float* __restrict__ c1) {
    __shared__ int   s[512];
    __shared__ float w2s[1280];
    int t = threadIdx.x;
    if (blockIdx.x == 0) {
        int run = 0;
        if (t < NB) {
            for (int b = 0; b < NBLK_BIN; ++b) {
                int v = blockHist[b * NB + t];
                blockHist[b * NB + t] = run;   // per-bucket exclusive over blocks
                run += v;
            }
        }
        s[t] = (t < NB) ? run : 0;
        __syncthreads();
        for (int st = 1; st < 512; st <<= 1) {
            int tmp = (t >= st) ? s[t - st] : 0;
            __syncthreads();
            s[t] += tmp;
            __syncthreads();
        }
        if (t < NB) bucketBase[t] = s[t] - run;   // exclusive
        if (t == NB - 1) bucketBase[NB] = s[t];   // = E_EDGES
    } else {
        for (int i = t; i < 1280; i += 512) w2s[i] = W2[i];
        __syncthreads();
        if (t < 128) {
            float acc[NCLS];
            #pragma unroll
            for (int j = 0; j < NCLS; ++j) acc[j] = 0.f;
            for (int m = 0; m < 128; ++m) {
                float w1mk = W1[m * 128 + t];    // coalesced column read
                #pragma unroll
                for (int j = 0; j < NCLS; ++j) acc[j] += w2s[j * 128 + m] * w1mk;
            }
            #pragma unroll
            for (int j = 0; j < NCLS; ++j) W12[j * 128 + t] = acc[j];
        } else if (t < 144) {
            int j = t - 128;
            float acc = 0.f;
            if (j < NCLS)
                for (int m = 0; m < 128; ++m) acc += W2[j * 128 + m] * b1[m];
            c1[j] = (j < NCLS) ? acc : 0.f;
        }
    }
}

// ------- bin edges into bucketed packed array (deterministic chunks) ------
__global__ __launch_bounds__(256) void k_bin(const int* __restrict__ ei,
                                             const int* __restrict__ blockHist,
                                             const int* __restrict__ bucketBase,
                                             unsigned* __restrict__ binned) {
    __shared__ int h[NB];
    __shared__ int chunk[NB];
    int t = threadIdx.x;
    for (int i = t; i < NB; i += 256) {
        h[i] = 0;
        chunk[i] = bucketBase[i] + blockHist[blockIdx.x * NB + i];
    }
    __syncthreads();
    int base = blockIdx.x * EPB;
    int end  = min(base + EPB, E_EDGES);
    const int* col = ei + E_EDGES;
    for (int e = base + t; e < end; e += 256) {
        int c = col[e];
        int r = ei[e];
        int k = c >> 8;
        int slot = chunk[k] + atomicAdd(&h[k], 1);   // LDS-local rank only
        binned[slot] = ((unsigned)r << 8) | (unsigned)(c & 255);
    }
}

// ------- per-bucket: degrees, offsets, dis, csr fill + fused g1 -----------
// epilogue: thread t computes g1 row of its node (dis already in register).
__global__ __launch_bounds__(256) void k_build(const unsigned* __restrict__ binned,
                                               const int* __restrict__ bucketBase,
                                               int2* __restrict__ od,
                                               float* __restrict__ dis,
                                               int* __restrict__ csr,
                                               const float* __restrict__ x,
                                               const float* __restrict__ W12,
                                               __half2* __restrict__ g1h) {
    __shared__ int cnt[BW];
    __shared__ int sc[BW];
    __shared__ int eoff[BW];
    __shared__ int cur[BW];
    int k = blockIdx.x;
    int t = threadIdx.x;
    cnt[t] = 0;
    __syncthreads();
    int s0 = bucketBase[k], s1 = bucketBase[k + 1];
    for (int i = s0 + t; i < s1; i += 256)
        atomicAdd(&cnt[binned[i] & 255], 1);
    __syncthreads();
    int v = cnt[t];
    sc[t] = v;
    __syncthreads();
    for (int st = 1; st < 256; st <<= 1) {
        int tmp = (t >= st) ? sc[t - st] : 0;
        __syncthreads();
        sc[t] += tmp;
        __syncthreads();
    }
    eoff[t] = sc[t] - v;   // exclusive
    cur[t] = 0;
    int node = k * BW + t;
    float d = rsqrtf((float)(v + 1));
    if (node < N_NODES) {
        od[node] = make_int2(s0 + eoff[t], v);
        dis[node] = d;
    }
    __syncthreads();
    for (int i = s0 + t; i < s1; i += 256) {
        unsigned p = binned[i];
        int lc = p & 255;
        int r  = p >> 8;
        int pos = s0 + eoff[lc] + atomicAdd(&cur[lc], 1);
        csr[pos] = r;
    }

    // ---- fused g1: g1h[node] = fp16( d * (x[node] @ W12^T) ) ----
    if (node < N_NODES) {
        const float4* x4 = (const float4*)x;
        float acc[NCLS];
        #pragma unroll
        for (int j = 0; j < NCLS; ++j) acc[j] = 0.f;

        #pragma unroll
        for (int k4 = 0; k4 < 32; ++k4) {
            float4 xv = x4[node * 32 + k4];
            #pragma unroll
            for (int j = 0; j < NCLS; ++j) {
                const float* wj = &W12[j * 128 + k4 * 4];   // uniform -> s_load
                acc[j] += xv.x * wj[0] + xv.y * wj[1] + xv.z * wj[2] + xv.w * wj[3];
            }
        }

        __half2 hp[8];
        #pragma unroll
        for (int j = 0; j < 5; ++j)
            hp[j] = __floats2half2_rn(d * acc[2 * j], d * acc[2 * j + 1]);
        hp[5] = __floats2half2_rn(0.f, 0.f);
        hp[6] = hp[5];
        hp[7] = hp[5];
        uint4* dst = (uint4*)&g1h[node * 8];
        dst[0] = *(const uint4*)&hp[0];
        dst[1] = *(const uint4*)&hp[4];
    }
}

// ------- agg A: h2h = fp16( dc*(dc*acc + c1) ), acc = sum of scaled rows --
// 8-lane groups; lane j covers feats {2j, 2j+1}; f32 accumulation.
__global__ __launch_bounds__(256) void k_agg_a(const __half2* __restrict__ g1h,
                                               const float* __restrict__ dis,
                                               const int* __restrict__ csr,
                                               const int2* __restrict__ od,
                                               const float* __restrict__ c1,
                                               __half2* __restrict__ h2h) {
    int c = blockIdx.x * 32 + (threadIdx.x >> 3);
    int j = threadIdx.x & 7;
    if (c >= N_NODES) return;

    float2 acc = __half22float2(g1h[c * 8 + j]);   // self (pre-scaled)

    int2 odv  = od[c];
    int start = odv.x;
    int deg   = odv.y;
    int k = 0;
    if (deg >= 4) {
        int i0 = csr[start + 0], i1 = csr[start + 1];
        int i2 = csr[start + 2], i3 = csr[start + 3];
        for (; k + 8 <= deg; k += 4) {
            int n0 = csr[start + k + 4], n1 = csr[start + k + 5];
            int n2 = csr[start + k + 6], n3 = csr[start + k + 7];
            float2 a0 = __half22float2(g1h[i0 * 8 + j]);
            float2 a1 = __half22float2(g1h[i1 * 8 + j]);
            float2 a2 = __half22float2(g1h[i2 * 8 + j]);
            float2 a3 = __half22float2(g1h[i3 * 8 + j]);
            acc.x += (a0.x + a1.x) + (a2.x + a3.x);
            acc.y += (a0.y + a1.y) + (a2.y + a3.y);
            i0 = n0; i1 = n1; i2 = n2; i3 = n3;
        }
        float2 a0 = __half22float2(g1h[i0 * 8 + j]);
        float2 a1 = __half22float2(g1h[i1 * 8 + j]);
        float2 a2 = __half22float2(g1h[i2 * 8 + j]);
        float2 a3 = __half22float2(g1h[i3 * 8 + j]);
        acc.x += (a0.x + a1.x) + (a2.x + a3.x);
        acc.y += (a0.y + a1.y) + (a2.y + a3.y);
        k += 4;
    }
    for (; k < deg; ++k) {
        float2 a = __half22float2(g1h[csr[start + k] * 8 + j]);
        acc.x += a.x;
        acc.y += a.y;
    }

    float dc = dis[c];
    float ox = dc * (dc * acc.x + c1[2 * j]);       // j>=5: acc=0,c1=0 -> 0
    float oy = dc * (dc * acc.y + c1[2 * j + 1]);
    h2h[c * 8 + j] = __floats2half2_rn(ox, oy);
}

// ------- agg B: out = dc*acc + b2 (compact N x 10 f32 output) -------------
__global__ __launch_bounds__(256) void k_agg_b(const __half2* __restrict__ h2h,
                                               const float* __restrict__ dis,
                                               const int* __restrict__ csr,
                                               const int2* __restrict__ od,
                                               const float* __restrict__ b2,
                                               float* __restrict__ out) {
    int c = blockIdx.x * 32 + (threadIdx.x >> 3);
    int j = threadIdx.x & 7;
    if (c >= N_NODES) return;

    float2 acc = __half22float2(h2h[c * 8 + j]);   // self (pre-scaled)

    int2 odv  = od[c];
    int start = odv.x;
    int deg   = odv.y;
    int k = 0;
    if (deg >= 4) {
        int i0 = csr[start + 0], i1 = csr[start + 1];
        int i2 = csr[start + 2], i3 = csr[start + 3];
        for (; k + 8 <= deg; k += 4) {
            int n0 = csr[start + k + 4], n1 = csr[start + k + 5];
            int n2 = csr[start + k + 6], n3 = csr[start + k + 7];
            float2 a0 = __half22float2(h2h[i0 * 8 + j]);
            float2 a1 = __half22float2(h2h[i1 * 8 + j]);
            float2 a2 = __half22float2(h2h[i2 * 8 + j]);
            float2 a3 = __half22float2(h2h[i3 * 8 + j]);
            acc.x += (a0.x + a1.x) + (a2.x + a3.x);
            acc.y += (a0.y + a1.y) + (a2.y + a3.y);
            i0 = n0; i1 = n1; i2 = n2; i3 = n3;
        }
        float2 a0 = __half22float2(h2h[i0 * 8 + j]);
        float2 a1 = __half22float2(h2h[i1 * 8 + j]);
        float2 a2 = __half22float2(h2h[i2 * 8 + j]);
        float2 a3 = __half22float2(h2h[i3 * 8 + j]);
        acc.x += (a0.x + a1.x) + (a2.x + a3.x);
        acc.y += (a0.y + a1.y) + (a2.y + a3.y);
        k += 4;
    }
    for (; k < deg; ++k) {
        float2 a = __half22float2(h2h[csr[start + k] * 8 + j]);
        acc.x += a.x;
        acc.y += a.y;
    }

    if (j < 5) {
        float dc = dis[c];
        float2 o;
        o.x = dc * acc.x + b2[2 * j];
        o.y = dc * acc.y + b2[2 * j + 1];
        *(float2*)&out[c * NCLS + 2 * j] = o;
    }
}

extern "C" void kernel_launch(void* const* d_in, const int* in_sizes, int n_in,
                              void* d_out, int out_size, void* d_ws, size_t ws_size,
                              hipStream_t stream) {
    const float* x  = (const float*)d_in[0];
    const int*   ei = (const int*)d_in[1];   // [2, E] int32
    const float* W1 = (const float*)d_in[2];
    const float* b1 = (const float*)d_in[3];
    const float* W2 = (const float*)d_in[4];
    const float* b2 = (const float*)d_in[5];
    float* out = (float*)d_out;

    char* ws = (char*)d_ws;
    int*      bucketBase = (int*)(ws + 0);                  // NB+1 ints
    float*    W12        = (float*)(ws + 4096);             // 5 KB
    float*    c1         = (float*)(ws + 16384);            // 64 B (16 padded)
    int*      blockHist  = (int*)(ws + 32768);              // 196*391 ints ~300 KB
    int2*     od         = (int2*)(ws + (1 << 20));         // 800 KB
    float*    dis        = (float*)(ws + (3 << 20));        // 400 KB
    unsigned* binned     = (unsigned*)(ws + (4 << 20));     // 6.4 MB
    int*      csr        = (int*)(ws + (12 << 20));         // 6.4 MB
    __half2*  g1h        = (__half2*)(ws + (20 << 20));     // 3.2 MB
    __half2*  h2h        = (__half2*)(ws + (24 << 20));     // 3.2 MB

    k_hist<<<NBLK_BIN, 256, 0, stream>>>(ei + E_EDGES, blockHist);
    k_scan_w12<<<2, 512, 0, stream>>>(blockHist, bucketBase, W1, W2, b1, W12, c1);
    k_bin<<<NBLK_BIN, 256, 0, stream>>>(ei, blockHist, bucketBase, binned);
    k_build<<<NB, 256, 0, stream>>>(binned, bucketBase, od, dis, csr, x, W12, g1h);

    k_agg_a<<<(N_NODES + 31) / 32, 256, 0, stream>>>(g1h, dis, csr, od, c1, h2h);
    k_agg_b<<<(N_NODES + 31) / 32, 256, 0, stream>>>(h2h, dis, csr, od, b2, out);
}

// Round 12
// 103.974 us; speedup vs baseline: 2.8590x; 1.0186x over previous
//
#include <hip/hip_runtime.h>
#include <hip/hip_fp16.h>

#define N_NODES 100000
#define E_EDGES 1600000
#define NCLS 10

#define BW 256                       // bucket width in nodes
#define NB 391                       // ceil(N_NODES / BW)
#define EPB 8192                     // edges per binning block
#define NBLK_BIN 196                 // ceil(E_EDGES / EPB)

// ------- blocks 0..195: per-block bucket histogram; block 196: W12,c1 -----
__global__ __launch_bounds__(256) void k_hist_w12(const int* __restrict__ col,
                                                  int* __restrict__ blockHist,
                                                  const float* __restrict__ W1,
                                                  const float* __restrict__ W2,
                                                  const float* __restrict__ b1,
                                                  float* __restrict__ W12,
                                                  float* __restrict__ c1) {
    __shared__ int   h[NB];
    __shared__ float w2s[1280];
    int t = threadIdx.x;
    if (blockIdx.x < NBLK_BIN) {
        for (int i = t; i < NB; i += 256) h[i] = 0;
        __syncthreads();
        int base = blockIdx.x * EPB;
        int end  = min(base + EPB, E_EDGES);
        for (int e = base + t; e < end; e += 256)
            atomicAdd(&h[col[e] >> 8], 1);
        __syncthreads();
        for (int i = t; i < NB; i += 256)
            blockHist[blockIdx.x * NB + i] = h[i];
    } else {
        for (int i = t; i < 1280; i += 256) w2s[i] = W2[i];
        __syncthreads();
        if (t < 128) {
            float acc[NCLS];
            #pragma unroll
            for (int j = 0; j < NCLS; ++j) acc[j] = 0.f;
            for (int m = 0; m < 128; ++m) {
                float w1mk = W1[m * 128 + t];    // coalesced column read
                #pragma unroll
                for (int j = 0; j < NCLS; ++j) acc[j] += w2s[j * 128 + m] * w1mk;
            }
            #pragma unroll
            for (int j = 0; j < NCLS; ++j) W12[j * 128 + t] = acc[j];
        } else if (t < 144) {
            int j = t - 128;
            float acc = 0.f;
            if (j < NCLS)
                for (int m = 0; m < 128; ++m) acc += W2[j * 128 + m] * b1[m];
            c1[j] = (j < NCLS) ? acc : 0.f;
        }
    }
}

// ------- block 0: deterministic offset scan; blocks 1..196: g1u -----------
// g1u[row] = x[row] @ W12^T (unscaled, f32, padded 16)
__global__ __launch_bounds__(512) void k_scan_g1(int* __restrict__ blockHist,
                                                 int* __restrict__ bucketBase,
                                                 const float* __restrict__ x,
                                                 const float* __restrict__ W12,
                                                 float* __restrict__ g1u) {
    __shared__ int s[512];
    int t = threadIdx.x;
    if (blockIdx.x == 0) {
        int run = 0;
        if (t < NB) {
            for (int b = 0; b < NBLK_BIN; ++b) {
                int v = blockHist[b * NB + t];
                blockHist[b * NB + t] = run;   // per-bucket exclusive over blocks
                run += v;
            }
        }
        s[t] = (t < NB) ? run : 0;
        __syncthreads();
        for (int st = 1; st < 512; st <<= 1) {
            int tmp = (t >= st) ? s[t - st] : 0;
            __syncthreads();
            s[t] += tmp;
            __syncthreads();
        }
        if (t < NB) bucketBase[t] = s[t] - run;   // exclusive
        if (t == NB - 1) bucketBase[NB] = s[t];   // = E_EDGES
    } else {
        int row = (blockIdx.x - 1) * 512 + t;
        if (row >= N_NODES) return;

        const float4* x4 = (const float4*)x;
        float acc[NCLS];
        #pragma unroll
        for (int j = 0; j < NCLS; ++j) acc[j] = 0.f;

        #pragma unroll
        for (int k4 = 0; k4 < 32; ++k4) {
            float4 xv = x4[row * 32 + k4];
            #pragma unroll
            for (int j = 0; j < NCLS; ++j) {
                const float* wj = &W12[j * 128 + k4 * 4];   // uniform -> s_load
                acc[j] += xv.x * wj[0] + xv.y * wj[1] + xv.z * wj[2] + xv.w * wj[3];
            }
        }

        float4* dst = (float4*)&g1u[row * 16];
        dst[0] = make_float4(acc[0], acc[1], acc[2], acc[3]);
        dst[1] = make_float4(acc[4], acc[5], acc[6], acc[7]);
        dst[2] = make_float4(acc[8], acc[9], 0.f, 0.f);
    }
}

// ------- bin edges into bucketed packed array (deterministic chunks) ------
__global__ __launch_bounds__(256) void k_bin(const int* __restrict__ ei,
                                             const int* __restrict__ blockHist,
                                             const int* __restrict__ bucketBase,
                                             unsigned* __restrict__ binned) {
    __shared__ int h[NB];
    __shared__ int chunk[NB];
    int t = threadIdx.x;
    for (int i = t; i < NB; i += 256) {
        h[i] = 0;
        chunk[i] = bucketBase[i] + blockHist[blockIdx.x * NB + i];
    }
    __syncthreads();
    int base = blockIdx.x * EPB;
    int end  = min(base + EPB, E_EDGES);
    const int* col = ei + E_EDGES;
    for (int e = base + t; e < end; e += 256) {
        int c = col[e];
        int r = ei[e];
        int k = c >> 8;
        int slot = chunk[k] + atomicAdd(&h[k], 1);   // LDS-local rank only
        binned[slot] = ((unsigned)r << 8) | (unsigned)(c & 255);
    }
}

// ------- per-bucket: degrees, offsets, dis, csr fill + g1 scale -----------
__global__ __launch_bounds__(256) void k_build(const unsigned* __restrict__ binned,
                                               const int* __restrict__ bucketBase,
                                               int2* __restrict__ od,
                                               float* __restrict__ dis,
                                               int* __restrict__ csr,
                                               const float* __restrict__ g1u,
                                               __half2* __restrict__ g1h) {
    __shared__ int cnt[BW];
    __shared__ int sc[BW];
    __shared__ int eoff[BW];
    __shared__ int cur[BW];
    int k = blockIdx.x;
    int t = threadIdx.x;
    cnt[t] = 0;
    __syncthreads();
    int s0 = bucketBase[k], s1 = bucketBase[k + 1];
    for (int i = s0 + t; i < s1; i += 256)
        atomicAdd(&cnt[binned[i] & 255], 1);
    __syncthreads();
    int v = cnt[t];
    sc[t] = v;
    __syncthreads();
    for (int st = 1; st < 256; st <<= 1) {
        int tmp = (t >= st) ? sc[t - st] : 0;
        __syncthreads();
        sc[t] += tmp;
        __syncthreads();
    }
    eoff[t] = sc[t] - v;   // exclusive
    cur[t] = 0;
    int node = k * BW + t;
    float d = rsqrtf((float)(v + 1));
    if (node < N_NODES) {
        od[node] = make_int2(s0 + eoff[t], v);
        dis[node] = d;

        // scale + pack g1: g1h[node] = fp16(d * g1u[node])
        const float4* g4 = (const float4*)&g1u[node * 16];
        float4 a = g4[0];
        float4 b = g4[1];
        float4 c = g4[2];
        __half2 hp[8];
        hp[0] = __floats2half2_rn(d * a.x, d * a.y);
        hp[1] = __floats2half2_rn(d * a.z, d * a.w);
        hp[2] = __floats2half2_rn(d * b.x, d * b.y);
        hp[3] = __floats2half2_rn(d * b.z, d * b.w);
        hp[4] = __floats2half2_rn(d * c.x, d * c.y);
        hp[5] = __floats2half2_rn(0.f, 0.f);
        hp[6] = hp[5];
        hp[7] = hp[5];
        uint4* dst = (uint4*)&g1h[node * 8];
        dst[0] = *(const uint4*)&hp[0];
        dst[1] = *(const uint4*)&hp[4];
    }
    __syncthreads();
    for (int i = s0 + t; i < s1; i += 256) {
        unsigned p = binned[i];
        int lc = p & 255;
        int r  = p >> 8;
        int pos = s0 + eoff[lc] + atomicAdd(&cur[lc], 1);
        csr[pos] = r;
    }
}

// ------- agg A: h2h = fp16( dc*(dc*acc + c1) ), acc = sum of scaled rows --
// 8-lane groups; lane j covers feats {2j, 2j+1}; f32 accumulation.
__global__ __launch_bounds__(256) void k_agg_a(const __half2* __restrict__ g1h,
                                               const float* __restrict__ dis,
                                               const int* __restrict__ csr,
                                               const int2* __restrict__ od,
                                               const float* __restrict__ c1,
                                               __half2* __restrict__ h2h) {
    int c = blockIdx.x * 32 + (threadIdx.x >> 3);
    int j = threadIdx.x & 7;
    if (c >= N_NODES) return;

    float2 acc = __half22float2(g1h[c * 8 + j]);   // self (pre-scaled)

    int2 odv  = od[c];
    int start = odv.x;
    int deg   = odv.y;
    int k = 0;
    if (deg >= 4) {
        int i0 = csr[start + 0], i1 = csr[start + 1];
        int i2 = csr[start + 2], i3 = csr[start + 3];
        for (; k + 8 <= deg; k += 4) {
            int n0 = csr[start + k + 4], n1 = csr[start + k + 5];
            int n2 = csr[start + k + 6], n3 = csr[start + k + 7];
            float2 a0 = __half22float2(g1h[i0 * 8 + j]);
            float2 a1 = __half22float2(g1h[i1 * 8 + j]);
            float2 a2 = __half22float2(g1h[i2 * 8 + j]);
            float2 a3 = __half22float2(g1h[i3 * 8 + j]);
            acc.x += (a0.x + a1.x) + (a2.x + a3.x);
            acc.y += (a0.y + a1.y) + (a2.y + a3.y);
            i0 = n0; i1 = n1; i2 = n2; i3 = n3;
        }
        float2 a0 = __half22float2(g1h[i0 * 8 + j]);
        float2 a1 = __half22float2(g1h[i1 * 8 + j]);
        float2 a2 = __half22float2(g1h[i2 * 8 + j]);
        float2 a3 = __half22float2(g1h[i3 * 8 + j]);
        acc.x += (a0.x + a1.x) + (a2.x + a3.x);
        acc.y += (a0.y + a1.y) + (a2.y + a3.y);
        k += 4;
    }
    for (; k < deg; ++k) {
        float2 a = __half22float2(g1h[csr[start + k] * 8 + j]);
        acc.x += a.x;
        acc.y += a.y;
    }

    float dc = dis[c];
    float ox = dc * (dc * acc.x + c1[2 * j]);       // j>=5: acc=0,c1=0 -> 0
    float oy = dc * (dc * acc.y + c1[2 * j + 1]);
    h2h[c * 8 + j] = __floats2half2_rn(ox, oy);
}

// ------- agg B: out = dc*acc + b2 (compact N x 10 f32 output) -------------
__global__ __launch_bounds__(256) void k_agg_b(const __half2* __restrict__ h2h,
                                               const float* __restrict__ dis,
                                               const int* __restrict__ csr,
                                               const int2* __restrict__ od,
                                               const float* __restrict__ b2,
                                               float* __restrict__ out) {
    int c = blockIdx.x * 32 + (threadIdx.x >> 3);
    int j = threadIdx.x & 7;
    if (c >= N_NODES) return;

    float2 acc = __half22float2(h2h[c * 8 + j]);   // self (pre-scaled)

    int2 odv  = od[c];
    int start = odv.x;
    int deg   = odv.y;
    int k = 0;
    if (deg >= 4) {
        int i0 = csr[start + 0], i1 = csr[start + 1];
        int i2 = csr[start + 2], i3 = csr[start + 3];
        for (; k + 8 <= deg; k += 4) {
            int n0 = csr[start + k + 4], n1 = csr[start + k + 5];
            int n2 = csr[start + k + 6], n3 = csr[start + k + 7];
            float2 a0 = __half22float2(h2h[i0 * 8 + j]);
            float2 a1 = __half22float2(h2h[i1 * 8 + j]);
            float2 a2 = __half22float2(h2h[i2 * 8 + j]);
            float2 a3 = __half22float2(h2h[i3 * 8 + j]);
            acc.x += (a0.x + a1.x) + (a2.x + a3.x);
            acc.y += (a0.y + a1.y) + (a2.y + a3.y);
            i0 = n0; i1 = n1; i2 = n2; i3 = n3;
        }
        float2 a0 = __half22float2(h2h[i0 * 8 + j]);
        float2 a1 = __half22float2(h2h[i1 * 8 + j]);
        float2 a2 = __half22float2(h2h[i2 * 8 + j]);
        float2 a3 = __half22float2(h2h[i3 * 8 + j]);
        acc.x += (a0.x + a1.x) + (a2.x + a3.x);
        acc.y += (a0.y + a1.y) + (a2.y + a3.y);
        k += 4;
    }
    for (; k < deg; ++k) {
        float2 a = __half22float2(h2h[csr[start + k] * 8 + j]);
        acc.x += a.x;
        acc.y += a.y;
    }

    if (j < 5) {
        float dc = dis[c];
        float2 o;
        o.x = dc * acc.x + b2[2 * j];
        o.y = dc * acc.y + b2[2 * j + 1];
        *(float2*)&out[c * NCLS + 2 * j] = o;
    }
}

extern "C" void kernel_launch(void* const* d_in, const int* in_sizes, int n_in,
                              void* d_out, int out_size, void* d_ws, size_t ws_size,
                              hipStream_t stream) {
    const float* x  = (const float*)d_in[0];
    const int*   ei = (const int*)d_in[1];   // [2, E] int32
    const float* W1 = (const float*)d_in[2];
    const float* b1 = (const float*)d_in[3];
    const float* W2 = (const float*)d_in[4];
    const float* b2 = (const float*)d_in[5];
    float* out = (float*)d_out;

    char* ws = (char*)d_ws;
    int*      bucketBase = (int*)(ws + 0);                  // NB+1 ints
    float*    W12        = (float*)(ws + 4096);             // 5 KB
    float*    c1         = (float*)(ws + 16384);            // 64 B (16 padded)
    int*      blockHist  = (int*)(ws + 32768);              // 196*391 ints ~300 KB
    int2*     od         = (int2*)(ws + (1 << 20));         // 800 KB
    float*    dis        = (float*)(ws + (3 << 20));        // 400 KB
    unsigned* binned     = (unsigned*)(ws + (4 << 20));     // 6.4 MB
    int*      csr        = (int*)(ws + (12 << 20));         // 6.4 MB
    float*    g1u        = (float*)(ws + (20 << 20));       // 6.4 MB (f32 x16)
    __half2*  g1h        = (__half2*)(ws + (28 << 20));     // 3.2 MB
    __half2*  h2h        = (__half2*)(ws + (32 << 20));     // 3.2 MB

    k_hist_w12<<<NBLK_BIN + 1, 256, 0, stream>>>(ei + E_EDGES, blockHist,
                                                 W1, W2, b1, W12, c1);
    k_scan_g1<<<NBLK_BIN + 1, 512, 0, stream>>>(blockHist, bucketBase, x, W12, g1u);
    k_bin<<<NBLK_BIN, 256, 0, stream>>>(ei, blockHist, bucketBase, binned);
    k_build<<<NB, 256, 0, stream>>>(binned, bucketBase, od, dis, csr, g1u, g1h);

    k_agg_a<<<(N_NODES + 31) / 32, 256, 0, stream>>>(g1h, dis, csr, od, c1, h2h);
    k_agg_b<<<(N_NODES + 31) / 32, 256, 0, stream>>>(h2h, dis, csr, od, b2, out);
}